// Round 4
// baseline (1348.993 us; speedup 1.0000x reference)
//
#include <hip/hip_runtime.h>
#include <cstdint>
#include <cstddef>

typedef unsigned short u16;
typedef __attribute__((ext_vector_type(8))) short s8v;   // 8 bf16 in 4 VGPRs
typedef __attribute__((ext_vector_type(4))) float f4v;   // MFMA accumulator

#define D_MODEL 1024
#define D_INNER 2048
#define BT      8192   // B*T
#define TLEN    2048
#define NBATCH  4

struct alignas(8) U16x4 { u16 x, y, z, w; };

__device__ __forceinline__ u16 f2bf(float f) {
  union { float f; unsigned u; } c; c.f = f;
  unsigned r = c.u + 0x7FFFu + ((c.u >> 16) & 1u);   // RNE
  return (u16)(r >> 16);
}
__device__ __forceinline__ float bf2f(u16 b) {
  union { unsigned u; float f; } c; c.u = ((unsigned)b) << 16;
  return c.f;
}
// bf16 unpack from packed pair (u32): low ch / high ch
__device__ __forceinline__ float blo(unsigned u) {
  union { unsigned u; float f; } c; c.u = u << 16; return c.f;
}
__device__ __forceinline__ float bhi(unsigned u) {
  union { unsigned u; float f; } c; c.u = u & 0xffff0000u; return c.f;
}
// pack two fp32 -> packed bf16 pair (round half up), lo in low 16
__device__ __forceinline__ unsigned pkbf(float lo, float hi) {
  union { float f; unsigned u; } a, b; a.f = lo; b.f = hi;
#if __has_builtin(__builtin_amdgcn_perm)
  return __builtin_amdgcn_perm(b.u + 0x8000u, a.u + 0x8000u, 0x07060302u);
#else
  return ((b.u + 0x8000u) & 0xffff0000u) | ((a.u + 0x8000u) >> 16);
#endif
}

// DPP wave-64 sum: VALU-pipe latency instead of ds_bpermute. Lane 63 = sum.
#define DPPADD(x, ctrl) \
  ((x) + __builtin_bit_cast(float, __builtin_amdgcn_update_dpp( \
       0, __builtin_bit_cast(int, (x)), (ctrl), 0xF, 0xF, true)))
__device__ __forceinline__ float wave_sum_dpp(float x) {
  x = DPPADD(x, 0x111);  // row_shr:1
  x = DPPADD(x, 0x112);  // row_shr:2
  x = DPPADD(x, 0x114);  // row_shr:4
  x = DPPADD(x, 0x118);  // row_shr:8
  x = DPPADD(x, 0x142);  // row_bcast:15
  x = DPPADD(x, 0x143);  // row_bcast:31
  return x;              // lane 63 = wave sum
}

// async global->LDS, 16B per lane; LDS dest must be wave-uniform base (+lane*16 by HW)
__device__ __forceinline__ void glds16(const u16* g, const u16* lds) {
  __builtin_amdgcn_global_load_lds(
      (const __attribute__((address_space(1))) unsigned int*)(uintptr_t)g,
      (__attribute__((address_space(3))) unsigned int*)(unsigned int)(uintptr_t)lds,
      16, 0, 0);
}

// C[m,n] = sum_k A[m,k]*B[n,k]; A: MxK row-major, B: NxK row-major (both bf16).
// EPI 0: split N=4096 -> Cb=xi bf16 (n<2048), Cb2=silu(z) bf16 (n>=2048)
// EPI 3: Cf = acc (final out)
// EPI 4: merged: n<2048 -> Cf = exp(sfac[n]*sigmoid(acc+bias[n])) (lam fp32)
//                n>=2048 -> Cb = bf16(acc + bias2[n-2048])        (v bf16)
template<int EPI>
__global__ __launch_bounds__(256, 2)
void gemm_nt(const u16* __restrict__ A, const u16* __restrict__ B,
             int M, int N, int K,
             float* __restrict__ Cf, u16* __restrict__ Cb, u16* __restrict__ Cb2,
             const float* __restrict__ bias, const float* __restrict__ sfac,
             const float* __restrict__ bias2)
{
  __shared__ u16 lA[128 * 32];
  __shared__ u16 lB[128 * 32];
  const int tid  = threadIdx.x;
  const int wave = tid >> 6, lane = tid & 63;
  const int wm = wave >> 1, wn = wave & 1;
  const int bm0 = blockIdx.y * 128, bn0 = blockIdx.x * 128;

  const int srow = lane >> 2;
  const int scol = (lane & 3) * 8;
  const u16* pa0 = A + (size_t)(bm0 + wave * 32 + srow) * K + scol;
  const u16* pa1 = pa0 + (size_t)16 * K;
  const u16* pb0 = B + (size_t)(bn0 + wave * 32 + srow) * K + scol;
  const u16* pb1 = pb0 + (size_t)16 * K;
  u16* la0 = lA + (wave * 32) * 32;
  u16* la1 = la0 + 16 * 32;
  u16* lb0 = lB + (wave * 32) * 32;
  u16* lb1 = lb0 + 16 * 32;

  const int fr = lane & 15, kq = lane >> 4;
  const u16* fA = lA + (wm * 64 + fr) * 32 + kq * 8;
  const u16* fB = lB + (wn * 64 + fr) * 32 + kq * 8;

  f4v acc[4][4];
  const f4v zf = {0.f, 0.f, 0.f, 0.f};
  for (int i = 0; i < 4; ++i)
    for (int j = 0; j < 4; ++j)
      acc[i][j] = zf;

  for (int k0 = 0; k0 < K; k0 += 32) {
    glds16(pa0 + k0, la0);
    glds16(pa1 + k0, la1);
    glds16(pb0 + k0, lb0);
    glds16(pb1 + k0, lb1);
    __syncthreads();
    s8v af[4], bfv[4];
#pragma unroll
    for (int i = 0; i < 4; ++i) af[i] = *(const s8v*)(fA + i * 16 * 32);
#pragma unroll
    for (int j = 0; j < 4; ++j) bfv[j] = *(const s8v*)(fB + j * 16 * 32);
#pragma unroll
    for (int i = 0; i < 4; ++i)
#pragma unroll
      for (int j = 0; j < 4; ++j)
        acc[i][j] = __builtin_amdgcn_mfma_f32_16x16x32_bf16(af[i], bfv[j], acc[i][j], 0, 0, 0);
    __syncthreads();
  }

  // C/D layout: col = lane&15, row = (lane>>4)*4 + reg
#pragma unroll
  for (int i = 0; i < 4; ++i) {
#pragma unroll
    for (int j = 0; j < 4; ++j) {
#pragma unroll
      for (int r = 0; r < 4; ++r) {
        const int gm = bm0 + wm * 64 + i * 16 + kq * 4 + r;
        const int gn = bn0 + wn * 64 + j * 16 + fr;
        const float val = acc[i][j][r];
        if (EPI == 0) {
          if (gn < D_INNER) {
            Cb[(size_t)gm * D_INNER + gn] = f2bf(val);
          } else {
            const float s = val / (1.f + __expf(-val));  // silu(z)
            Cb2[(size_t)gm * D_INNER + (gn - D_INNER)] = f2bf(s);
          }
        } else if (EPI == 4) {
          if (gn < D_INNER) {
            const float pre = val + bias[gn];
            const float sig = 1.f / (1.f + __expf(-pre));
            Cf[(size_t)gm * D_INNER + gn] = __expf(sfac[gn] * sig);
          } else {
            Cb[(size_t)gm * D_INNER + (gn - D_INNER)] = f2bf(val + bias2[gn - D_INNER]);
          }
        } else {
          Cf[(size_t)gm * N + gn] = val;
        }
      }
    }
  }
}

__global__ void conv_bf16_kernel(const float* __restrict__ in, u16* __restrict__ out, int n4)
{
  const int i = blockIdx.x * blockDim.x + threadIdx.x;
  if (i >= n4) return;
  const float4 x = ((const float4*)in)[i];
  U16x4 o; o.x = f2bf(x.x); o.y = f2bf(x.y); o.z = f2bf(x.z); o.w = f2bf(x.w);
  ((U16x4*)out)[i] = o;
}

__global__ void sfac_kernel(const float* __restrict__ omega, float* __restrict__ sfac)
{
  const int i = blockIdx.x * blockDim.x + threadIdx.x;
  if (i < D_INNER) sfac[i] = -8.f * log1pf(expf(omega[i]));  // -C*softplus(omega)
}

// v <- v * sqrt(2/(v.v)) per row; 1 wave per row, 4 rows per block.
__global__ __launch_bounds__(256)
void vscale_kernel(u16* __restrict__ v)
{
  const int row  = blockIdx.x * 4 + (threadIdx.x >> 6);
  const int lane = threadIdx.x & 63;
  uint4* p = (uint4*)(v + (size_t)row * D_INNER + lane * 32);  // 32 ch/lane
  uint4 a[4];
#pragma unroll
  for (int i = 0; i < 4; ++i) a[i] = p[i];
  float s = 0.f;
#pragma unroll
  for (int i = 0; i < 4; ++i) {
    const unsigned w[4] = {a[i].x, a[i].y, a[i].z, a[i].w};
#pragma unroll
    for (int j = 0; j < 4; ++j) {
      const float f0 = blo(w[j]), f1 = bhi(w[j]);
      s += f0 * f0 + f1 * f1;
    }
  }
  s += __shfl_down(s, 32); s += __shfl_down(s, 16); s += __shfl_down(s, 8);
  s += __shfl_down(s, 4);  s += __shfl_down(s, 2);  s += __shfl_down(s, 1);
  const float sc = sqrtf(2.f / __shfl(s, 0));
#pragma unroll
  for (int i = 0; i < 4; ++i) {
    const unsigned w[4] = {a[i].x, a[i].y, a[i].z, a[i].w};
    unsigned o[4];
#pragma unroll
    for (int j = 0; j < 4; ++j) o[j] = pkbf(blo(w[j]) * sc, bhi(w[j]) * sc);
    uint4 ov; ov.x = o[0]; ov.y = o[1]; ov.z = o[2]; ov.w = o[3];
    p[i] = ov;
  }
}

// Pair cross-terms (h-independent), one wave per even t:
//   C1_t = bf16(v_{t+1}⊙l_t) · v_t   (ROUNDED w — must match scan's in-kernel w)
//   C2_t = v_{t+1} · ((1-l_t) ⊙ x_t)
__global__ __launch_bounds__(256)
void pairprep_kernel(const u16* __restrict__ vs, const float* __restrict__ lam,
                     const u16* __restrict__ xi,
                     float* __restrict__ C1, float* __restrict__ C2)
{
  const int r = blockIdx.x * 4 + (threadIdx.x >> 6);  // r = b*1024 + t/2
  const int lane = threadIdx.x & 63;
  const int b = r >> 10;
  const int t = (r & 1023) * 2;
  const size_t o0 = ((size_t)b * TLEN + t) * D_INNER + (size_t)lane * 32;
  const size_t o1 = o0 + D_INNER;
  const uint4*  pv0 = (const uint4*)(vs + o0);
  const uint4*  pv1 = (const uint4*)(vs + o1);
  const uint4*  px0 = (const uint4*)(xi + o0);
  const float4* pl0 = (const float4*)(lam + o0);
  float c1 = 0.f, c2 = 0.f;
#pragma unroll
  for (int i = 0; i < 4; ++i) {
    const uint4 v0 = pv0[i], v1 = pv1[i], x0 = px0[i];
    const float4 la = pl0[2 * i], lb2 = pl0[2 * i + 1];
    const unsigned v0w[4] = {v0.x, v0.y, v0.z, v0.w};
    const unsigned v1w[4] = {v1.x, v1.y, v1.z, v1.w};
    const unsigned x0w[4] = {x0.x, x0.y, x0.z, x0.w};
    const float lf[8] = {la.x, la.y, la.z, la.w, lb2.x, lb2.y, lb2.z, lb2.w};
#pragma unroll
    for (int q = 0; q < 4; ++q) {
      const float va = blo(v0w[q]), vb = bhi(v0w[q]);
      const float ua = blo(v1w[q]), ub = bhi(v1w[q]);
      const float xa = blo(x0w[q]), xb = bhi(x0w[q]);
      const unsigned ow = pkbf(ua * lf[2 * q], ub * lf[2 * q + 1]);
      c1 += blo(ow) * va + bhi(ow) * vb;          // rounded w
      c2 += ua * (1.f - lf[2 * q]) * xa + ub * (1.f - lf[2 * q + 1]) * xb;
    }
  }
  c1 = wave_sum_dpp(c1);
  c2 = wave_sum_dpp(c2);
  if (lane == 63) { C1[r] = c1; C2[r] = c2; }
}

// ---- paired scan, register-resident pipeline (no structs in scratch) ----
struct PR {  // 42 VGPRs
  uint4 v0, v1, x0, x1, z0, z1;
  float4 l0a, l0b, l1a, l1b;
  float c1, c2;
};

__device__ __forceinline__ PR load_pr(const u16* __restrict__ xi,
                                      const u16* __restrict__ sz,
                                      const u16* __restrict__ vs,
                                      const float* __restrict__ lam,
                                      const float* __restrict__ C1,
                                      const float* __restrict__ C2,
                                      size_t base, int cb0, int t)
{
  PR p;
  const size_t o0 = base + (size_t)t * D_INNER;
  const size_t o1 = o0 + D_INNER;
  p.v0 = *(const uint4*)(vs + o0);
  p.v1 = *(const uint4*)(vs + o1);
  p.x0 = *(const uint4*)(xi + o0);
  p.x1 = *(const uint4*)(xi + o1);
  p.z0 = *(const uint4*)(sz + o0);
  p.z1 = *(const uint4*)(sz + o1);
  const float4* l0p = (const float4*)(lam + o0);
  p.l0a = l0p[0]; p.l0b = l0p[1];
  const float4* l1p = (const float4*)(lam + o1);
  p.l1a = l1p[0]; p.l1b = l1p[1];
  p.c1 = C1[cb0 + (t >> 1)];
  p.c2 = C2[cb0 + (t >> 1)];
  return p;
}

// cur: by-value snapshot (SSA). slot: pipeline register set to refill (t+4).
__device__ __forceinline__ void pair_body(
    PR cur, PR& slot, int t, float (&h)[8],
    const u16* __restrict__ xi, const u16* __restrict__ sz,
    const u16* __restrict__ vs, const float* __restrict__ lam,
    const float* __restrict__ C1, const float* __restrict__ C2,
    u16* __restrict__ gh, size_t base, int cb0, int wave, int lane,
    float (&rP)[2][4], float (&rQ)[2][4])
{
  // refill the pipeline first — loads issue immediately, consumed 2 bodies later
  if (t + 4 <= 2046)
    slot = load_pr(xi, sz, vs, lam, C1, C2, base, cb0, t + 4);

  const unsigned vw[4]  = {cur.v0.x, cur.v0.y, cur.v0.z, cur.v0.w};
  const unsigned v1w[4] = {cur.v1.x, cur.v1.y, cur.v1.z, cur.v1.w};
  const float lf0[8] = {cur.l0a.x, cur.l0a.y, cur.l0a.z, cur.l0a.w,
                        cur.l0b.x, cur.l0b.y, cur.l0b.z, cur.l0b.w};
  const float lf1[8] = {cur.l1a.x, cur.l1a.y, cur.l1a.z, cur.l1a.w,
                        cur.l1b.x, cur.l1b.y, cur.l1b.z, cur.l1b.w};
  float vf[8], v1f[8], wf[8];
  float P0 = 0.f, P1 = 0.f, Q0 = 0.f, Q1 = 0.f;
#pragma unroll
  for (int q = 0; q < 4; ++q) {
    vf[2*q]   = blo(vw[q]);
    vf[2*q+1] = bhi(vw[q]);
    v1f[2*q]   = blo(v1w[q]);
    v1f[2*q+1] = bhi(v1w[q]);
    // w = bf16(l0 ⊙ v1) — identical rounding to pairprep's C1 term
    const unsigned wq = pkbf(v1f[2*q] * lf0[2*q], v1f[2*q+1] * lf0[2*q+1]);
    wf[2*q]   = blo(wq);
    wf[2*q+1] = bhi(wq);
    P0 = __builtin_fmaf(vf[2*q],   h[2*q],   P0);
    P1 = __builtin_fmaf(vf[2*q+1], h[2*q+1], P1);
    Q0 = __builtin_fmaf(wf[2*q],   h[2*q],   Q0);
    Q1 = __builtin_fmaf(wf[2*q+1], h[2*q+1], Q1);
  }
  float P = wave_sum_dpp(P0 + P1);
  float Q = wave_sum_dpp(Q0 + Q1);
  const int par = (t >> 1) & 1;
  if (lane == 63) { rP[par][wave] = P; rQ[par][wave] = Q; }
  // order the LDS write only; do NOT drain vmcnt (prefetch stays in flight)
  asm volatile("s_waitcnt lgkmcnt(0)\n\ts_barrier" ::: "memory");
  const float4 sp = *(const float4*)rP[par];
  const float4 sq = *(const float4*)rQ[par];
  const float a0 = (sp.x + sp.y) + (sp.z + sp.w);
  const float a1 = __builtin_fmaf(-a0, cur.c1, (sq.x + sq.y) + (sq.z + sq.w) + cur.c2);
  const unsigned xw0[4] = {cur.x0.x, cur.x0.y, cur.x0.z, cur.x0.w};
  const unsigned xw1[4] = {cur.x1.x, cur.x1.y, cur.x1.z, cur.x1.w};
  const unsigned zw0[4] = {cur.z0.x, cur.z0.y, cur.z0.z, cur.z0.w};
  const unsigned zw1[4] = {cur.z1.x, cur.z1.y, cur.z1.z, cur.z1.w};
  unsigned ow0[4], ow1[4];
#pragma unroll
  for (int q = 0; q < 4; ++q) {
    const float A0 = blo(xw0[q]), A1 = bhi(xw0[q]);
    const float B0 = blo(xw1[q]), B1 = bhi(xw1[q]);
    float t0 = __builtin_fmaf(vf[2*q],   -a0, h[2*q]);
    float t1 = __builtin_fmaf(vf[2*q+1], -a0, h[2*q+1]);
    t0 = __builtin_fmaf(lf0[2*q],   t0 - A0, A0);   // h_t
    t1 = __builtin_fmaf(lf0[2*q+1], t1 - A1, A1);
    ow0[q] = pkbf(blo(zw0[q]) * t0, bhi(zw0[q]) * t1);
    const float u0 = __builtin_fmaf(v1f[2*q],   -a1, t0);
    const float u1 = __builtin_fmaf(v1f[2*q+1], -a1, t1);
    h[2*q]   = __builtin_fmaf(lf1[2*q],   u0 - B0, B0);   // h_{t+1}
    h[2*q+1] = __builtin_fmaf(lf1[2*q+1], u1 - B1, B1);
    ow1[q] = pkbf(blo(zw1[q]) * h[2*q], bhi(zw1[q]) * h[2*q+1]);
  }
  const size_t oo = base + (size_t)t * D_INNER;
  uint4 o0; o0.x = ow0[0]; o0.y = ow0[1]; o0.z = ow0[2]; o0.w = ow0[3];
  uint4 o1; o1.x = ow1[0]; o1.y = ow1[1]; o1.z = ow1[2]; o1.w = ow1[3];
  *(uint4*)(gh + oo) = o0;
  *(uint4*)(gh + oo + D_INNER) = o1;
}

__global__ __launch_bounds__(256, 1)
void scan2_kernel(const u16* __restrict__ xi, const u16* __restrict__ sz,
                  const u16* __restrict__ vs, const float* __restrict__ lam,
                  const float* __restrict__ C1, const float* __restrict__ C2,
                  u16* __restrict__ gh)
{
  const int b = blockIdx.x, tid = threadIdx.x;
  const int wave = tid >> 6, lane = tid & 63;
  const size_t base = (size_t)b * TLEN * D_INNER + (size_t)tid * 8;
  const int cb0 = b * 1024;
  __shared__ __attribute__((aligned(16))) float rP[2][4], rQ[2][4];

  float h[8];
  {  // t = 0: h = xi, gh = sz*h
    const uint4 x0 = *(const uint4*)(xi + base);
    const uint4 z0 = *(const uint4*)(sz + base);
    const unsigned xw[4] = {x0.x, x0.y, x0.z, x0.w};
    const unsigned zw[4] = {z0.x, z0.y, z0.z, z0.w};
    unsigned ow[4];
#pragma unroll
    for (int p = 0; p < 4; ++p) {
      h[2*p]   = blo(xw[p]);
      h[2*p+1] = bhi(xw[p]);
      ow[p] = pkbf(blo(zw[p]) * h[2*p], bhi(zw[p]) * h[2*p+1]);
    }
    uint4 out; out.x = ow[0]; out.y = ow[1]; out.z = ow[2]; out.w = ow[3];
    *(uint4*)(gh + base) = out;
  }

  PR A = load_pr(xi, sz, vs, lam, C1, C2, base, cb0, 2);
  PR B = load_pr(xi, sz, vs, lam, C1, C2, base, cb0, 4);

  {  // solo step t = 1
    const size_t o = base + D_INNER;
    const uint4 v1v = *(const uint4*)(vs + o);
    const uint4 x1v = *(const uint4*)(xi + o);
    const uint4 z1v = *(const uint4*)(sz + o);
    const float4* lp = (const float4*)(lam + o);
    const float4 la = lp[0], lb2 = lp[1];
    const unsigned vw[4] = {v1v.x, v1v.y, v1v.z, v1v.w};
    float vf[8];
    float P0 = 0.f, P1 = 0.f;
#pragma unroll
    for (int p = 0; p < 4; ++p) {
      vf[2*p]   = blo(vw[p]);
      vf[2*p+1] = bhi(vw[p]);
      P0 = __builtin_fmaf(vf[2*p],   h[2*p],   P0);
      P1 = __builtin_fmaf(vf[2*p+1], h[2*p+1], P1);
    }
    float P = wave_sum_dpp(P0 + P1);
    if (lane == 63) rP[0][wave] = P;
    asm volatile("s_waitcnt lgkmcnt(0)\n\ts_barrier" ::: "memory");
    const float4 sp = *(const float4*)rP[0];
    const float a = (sp.x + sp.y) + (sp.z + sp.w);
    const float lf[8] = {la.x, la.y, la.z, la.w, lb2.x, lb2.y, lb2.z, lb2.w};
    const unsigned xw[4] = {x1v.x, x1v.y, x1v.z, x1v.w};
    const unsigned zw[4] = {z1v.x, z1v.y, z1v.z, z1v.w};
    unsigned ow[4];
#pragma unroll
    for (int p = 0; p < 4; ++p) {
      const float X0 = blo(xw[p]), X1 = bhi(xw[p]);
      const float t0 = __builtin_fmaf(vf[2*p],   -a, h[2*p]);
      const float t1 = __builtin_fmaf(vf[2*p+1], -a, h[2*p+1]);
      h[2*p]   = __builtin_fmaf(lf[2*p],   t0 - X0, X0);
      h[2*p+1] = __builtin_fmaf(lf[2*p+1], t1 - X1, X1);
      ow[p] = pkbf(blo(zw[p]) * h[2*p], bhi(zw[p]) * h[2*p+1]);
    }
    uint4 out; out.x = ow[0]; out.y = ow[1]; out.z = ow[2]; out.w = ow[3];
    *(uint4*)(gh + o) = out;
  }

  for (int t = 2; t <= 2046; t += 4) {
    pair_body(A, A, t, h, xi, sz, vs, lam, C1, C2, gh, base, cb0, wave, lane, rP, rQ);
    if (t + 2 <= 2046)
      pair_body(B, B, t + 2, h, xi, sz, vs, lam, C1, C2, gh, base, cb0, wave, lane, rP, rQ);
  }
}

extern "C" void kernel_launch(void* const* d_in, const int* in_sizes, int n_in,
                              void* d_out, int out_size, void* d_ws, size_t ws_size,
                              hipStream_t stream)
{
  const float* x     = (const float*)d_in[0];
  const float* omega = (const float*)d_in[1];
  const float* Win   = (const float*)d_in[2];
  const float* Wl    = (const float*)d_in[3];
  const float* bl    = (const float*)d_in[4];
  const float* Wv    = (const float*)d_in[5];
  const float* bv    = (const float*)d_in[6];
  const float* Wout  = (const float*)d_in[7];
  float* out = (float*)d_out;
  (void)in_sizes; (void)n_in; (void)out_size; (void)ws_size;

  size_t off = 0;
  auto carve = [&](size_t bytes) -> void* {
    void* r = (char*)d_ws + off;
    off += (bytes + 255) & ~(size_t)255;
    return r;
  };
  u16*  x_bf    = (u16*)carve((size_t)BT * D_MODEL * 2);
  u16*  Win_bf  = (u16*)carve((size_t)2 * D_INNER * D_MODEL * 2);
  u16*  Wl_bf   = (u16*)carve((size_t)D_INNER * D_INNER * 2);     // [Wl; Wv] contiguous
  u16*  Wv_bf   = (u16*)carve((size_t)D_INNER * D_INNER * 2);
  u16*  Wout_bf = (u16*)carve((size_t)D_MODEL * D_INNER * 2);
  u16*  xi_bf   = (u16*)carve((size_t)BT * D_INNER * 2);
  u16*  sz_bf   = (u16*)carve((size_t)BT * D_INNER * 2);
  u16*  v_bf    = (u16*)carve((size_t)BT * D_INNER * 2);
  u16*  gh_bf   = (u16*)carve((size_t)BT * D_INNER * 2);
  float* lam    = (float*)carve((size_t)BT * D_INNER * 4);        // fp32: precision
  float* sfac   = (float*)carve((size_t)D_INNER * 4);
  float* C1     = (float*)carve((size_t)(BT / 2) * 4);
  float* C2     = (float*)carve((size_t)(BT / 2) * 4);

  conv_bf16_kernel<<<(BT * D_MODEL / 4 + 255) / 256, 256, 0, stream>>>(x, x_bf, BT * D_MODEL / 4);
  conv_bf16_kernel<<<(2 * D_INNER * D_MODEL / 4 + 255) / 256, 256, 0, stream>>>(Win, Win_bf, 2 * D_INNER * D_MODEL / 4);
  conv_bf16_kernel<<<(D_INNER * D_INNER / 4 + 255) / 256, 256, 0, stream>>>(Wl, Wl_bf, D_INNER * D_INNER / 4);
  conv_bf16_kernel<<<(D_INNER * D_INNER / 4 + 255) / 256, 256, 0, stream>>>(Wv, Wv_bf, D_INNER * D_INNER / 4);
  conv_bf16_kernel<<<(D_MODEL * D_INNER / 4 + 255) / 256, 256, 0, stream>>>(Wout, Wout_bf, D_MODEL * D_INNER / 4);
  sfac_kernel<<<(D_INNER + 255) / 256, 256, 0, stream>>>(omega, sfac);

  // xz = x @ Win^T  -> xi (bf16) | silu(z) (bf16)
  gemm_nt<0><<<dim3(4096 / 128, BT / 128), 256, 0, stream>>>(
      x_bf, Win_bf, BT, 4096, D_MODEL, nullptr, xi_bf, sz_bf, nullptr, nullptr, nullptr);
  // merged: lam = exp(sfac*sigmoid(xi@Wl^T+bl)) fp32 | v = xi@Wv^T+bv bf16
  gemm_nt<4><<<dim3(4096 / 128, BT / 128), 256, 0, stream>>>(
      xi_bf, Wl_bf, BT, 4096, D_INNER, lam, v_bf, nullptr, bl, sfac, bv);
  // v <- v*sqrt(2/(v.v))
  vscale_kernel<<<BT / 4, 256, 0, stream>>>(v_bf);
  // pair cross-terms C1, C2
  pairprep_kernel<<<BT / 2 / 4, 256, 0, stream>>>(v_bf, lam, xi_bf, C1, C2);
  // paired sequential scan -> gh = silu(z)*h (bf16)
  scan2_kernel<<<NBATCH, 256, 0, stream>>>(xi_bf, sz_bf, v_bf, lam, C1, C2, gh_bf);
  // out = gh @ Wout^T (fp32)
  gemm_nt<3><<<dim3(D_MODEL / 128, BT / 128), 256, 0, stream>>>(
      gh_bf, Wout_bf, BT, D_MODEL, D_INNER, out, nullptr, nullptr, nullptr, nullptr, nullptr);
}